// Round 5
// baseline (244.463 us; speedup 1.0000x reference)
//
#include <hip/hip_runtime.h>
#include <cstddef>

#define B_   2
#define T_   4096
#define D_   1024
#define H_   16
#define KD_  512
#define VD_  1024
#define NC_  64          // T/CHUNK
#define M_   (B_*T_)     // 8192
#define GR_  16
#define EPS_ 1e-5f
#define SCALE_ 0.17677669529663687f  // 32^-0.5
#define GNORM_INV_ (1.0f/16.0f)

// fused projection layout: cols [0,512)=q, [512,1024)=k, [1024,2048)=v,
// [2048,3072)=g, [3072,3200)=glow (only first 16 weight rows nonzero),
// [3200,3328) = zero pad so N is divisible by 256 for the 256^2 GEMM.
#define NF_   3328
#define NVALID_ 3200
#define Q0_   0
#define K0_   512
#define V0_   1024
#define G0_   2048
#define GL0_  3072

typedef __attribute__((ext_vector_type(8))) __bf16 bf16x8;
typedef __attribute__((ext_vector_type(4))) float f32x4;

__device__ inline unsigned short f2bf(float f) {
  unsigned int u = __float_as_uint(f);
  u = (u + 0x7fffu + ((u >> 16) & 1u)) >> 16;
  return (unsigned short)u;
}
__device__ inline float bf2f(unsigned short u) {
  return __uint_as_float((unsigned int)u << 16);
}
__device__ inline void unpack8(uint4 u, float* f) {
  f[0] = bf2f(u.x & 0xffff); f[1] = bf2f(u.x >> 16);
  f[2] = bf2f(u.y & 0xffff); f[3] = bf2f(u.y >> 16);
  f[4] = bf2f(u.z & 0xffff); f[5] = bf2f(u.z >> 16);
  f[6] = bf2f(u.w & 0xffff); f[7] = bf2f(u.w >> 16);
}
__device__ inline uint4 pack8(const unsigned short* s) {
  uint4 u;
  u.x = (unsigned int)s[0] | ((unsigned int)s[1] << 16);
  u.y = (unsigned int)s[2] | ((unsigned int)s[3] << 16);
  u.z = (unsigned int)s[4] | ((unsigned int)s[5] << 16);
  u.w = (unsigned int)s[6] | ((unsigned int)s[7] << 16);
  return u;
}

__device__ __forceinline__ void gload_lds16(const unsigned short* g, unsigned short* l) {
  __builtin_amdgcn_global_load_lds(
      (const __attribute__((address_space(1))) unsigned int*)g,
      (__attribute__((address_space(3))) unsigned int*)l, 16, 0, 0);
}

// ---------------- prep: weight transposes (+Wgk1 pad) AND x f32->bf16, one launch ----------------

__global__ __launch_bounds__(256) void k_prep(const float* __restrict__ x,
                                              const float* __restrict__ Wq,
                                              const float* __restrict__ Wk,
                                              const float* __restrict__ Wv,
                                              const float* __restrict__ Wg,
                                              const float* __restrict__ Wo,
                                              const float* __restrict__ Wgk1,
                                              unsigned short* __restrict__ xb,
                                              unsigned short* __restrict__ Wcat,
                                              unsigned short* __restrict__ woT) {
  __shared__ float tile[32][33];
  if (blockIdx.z >= 6) {
    int lin = ((blockIdx.z - 6) * 1024 + blockIdx.y * 32 + blockIdx.x) * 256 + threadIdx.x;
    int i = lin * 4;
    float4 f = *(const float4*)(x + i);
    ushort4 o;
    o.x = f2bf(f.x); o.y = f2bf(f.y); o.z = f2bf(f.z); o.w = f2bf(f.w);
    *(ushort4*)(xb + i) = o;
    return;
  }
  const float* in; unsigned short* out; int N;
  switch (blockIdx.z) {
    case 0: in = Wq;   out = Wcat + (size_t)Q0_ * D_;  N = 512;  break;
    case 1: in = Wk;   out = Wcat + (size_t)K0_ * D_;  N = 512;  break;
    case 2: in = Wv;   out = Wcat + (size_t)V0_ * D_;  N = 1024; break;
    case 3: in = Wg;   out = Wcat + (size_t)G0_ * D_;  N = 1024; break;
    case 4: in = Wo;   out = woT;                      N = 1024; break;
    default: in = Wgk1; out = Wcat + (size_t)GL0_ * D_; N = 128;  break;  // pad: cols >= 16 are 0
  }
  int n0 = blockIdx.x * 32, k0 = blockIdx.y * 32;
  if (n0 >= N) return;
  int tx = threadIdx.x & 31, ty = threadIdx.x >> 5;   // 32 x 8
  if (blockIdx.z == 5) {
#pragma unroll
    for (int p = 0; p < 4; ++p)
      tile[ty + p*8][tx] = (n0 + tx < GR_) ? in[(size_t)(k0 + ty + p*8) * GR_ + n0 + tx] : 0.0f;
  } else {
#pragma unroll
    for (int p = 0; p < 4; ++p)
      tile[ty + p*8][tx] = in[(size_t)(k0 + ty + p*8) * N + n0 + tx];
  }
  __syncthreads();
#pragma unroll
  for (int p = 0; p < 4; ++p)
    out[(size_t)(n0 + ty + p*8) * 1024 + k0 + tx] = f2bf(tile[tx][ty + p*8]);
}

// ---------------- bf16 MFMA GEMM: C(MxN) = A(MxK) * Bt(NxK)^T ----------------
// 128x128 tile, BK=64, 256 threads (4 waves 2x2), 16x16x32 MFMA.
// Kept for the output projection (N=1024 -> only 128 blocks at 256^2, half-chip).

template <typename OutT>
__global__ __launch_bounds__(256, 3) void k_gemm_bt(const unsigned short* __restrict__ A,
                                                    const unsigned short* __restrict__ Bt,
                                                    OutT* __restrict__ C,
                                                    int M, int N, int K) {
  __shared__ __align__(16) unsigned short sA[128 * 64];
  __shared__ __align__(16) unsigned short sB[128 * 64];
  const int tid  = threadIdx.x;
  const int lane = tid & 63;
  const int wave = tid >> 6;
  const int wr = wave >> 1, wc = wave & 1;
  const int quad = lane >> 4, l16 = lane & 15;

  const int g = blockIdx.x;
  const int xcd = g & 7, slot = g >> 3;
  const int bm0 = ((xcd << 3) | (slot & 7)) << 7;   // M-tile
  const int bn0 = (slot >> 3) << 7;                 // N-tile

  const int lrow = lane >> 3;                      // 0..7 (== row & 7)
  const int gcol = ((lane & 7) ^ lrow) * 8;        // swizzled source column
  const unsigned short* ga = A  + (size_t)(bm0 + wave * 8 + lrow) * K + gcol;
  const unsigned short* gb = Bt + (size_t)(bn0 + wave * 8 + lrow) * K + gcol;
  unsigned short* la = sA + wave * 8 * 64;
  unsigned short* lb = sB + wave * 8 * 64;

  f32x4 acc[4][4] = {};

  for (int k0 = 0; k0 < K; k0 += 64) {
#pragma unroll
    for (int it = 0; it < 4; ++it) {
      gload_lds16(ga + k0 + (size_t)it * 32 * K, la + it * 32 * 64);
      gload_lds16(gb + k0 + (size_t)it * 32 * K, lb + it * 32 * 64);
    }
    __syncthreads();
#pragma unroll
    for (int kk = 0; kk < 2; ++kk) {
      bf16x8 af[4], bfv[4];
#pragma unroll
      for (int i = 0; i < 4; ++i) {
        int row = wr * 64 + i * 16 + l16;
        int gg = (kk * 4 + quad) ^ (row & 7);
        af[i] = *(const bf16x8*)(sA + row * 64 + gg * 8);
      }
#pragma unroll
      for (int j = 0; j < 4; ++j) {
        int row = wc * 64 + j * 16 + l16;
        int gg = (kk * 4 + quad) ^ (row & 7);
        bfv[j] = *(const bf16x8*)(sB + row * 64 + gg * 8);
      }
#pragma unroll
      for (int i = 0; i < 4; ++i)
#pragma unroll
        for (int j = 0; j < 4; ++j)
          acc[i][j] = __builtin_amdgcn_mfma_f32_16x16x32_bf16(af[i], bfv[j], acc[i][j], 0, 0, 0);
    }
    __syncthreads();
  }

#pragma unroll
  for (int i = 0; i < 4; ++i) {
    int row0 = bm0 + wr * 64 + i * 16 + quad * 4;
#pragma unroll
    for (int j = 0; j < 4; ++j) {
      int col = bn0 + wc * 64 + j * 16 + l16;
#pragma unroll
      for (int r = 0; r < 4; ++r) {
        float v = acc[i][j][r];
        if constexpr (sizeof(OutT) == 2)
          C[(size_t)(row0 + r) * N + col] = (OutT)f2bf(v);
        else
          C[(size_t)(row0 + r) * N + col] = (OutT)v;
      }
    }
  }
}

// ---------------- 256x256 4-phase counted-vmcnt GEMM v3 (bf16 out) ----------------
// 512 threads = 8 waves (2M x 4N), per-wave C = 128x64, BK=64, LDS 128 KiB dbuf.
// v3 fixes vs the round-1/2 attempt (which pinned at 32% MfmaUtil):
//  * fragment loads via inline-asm ds_read_b128 (AS3 operand) -- opaque to the
//    compiler's LDS alias analysis, so it cannot insert per-phase vmcnt drains
//    against the in-flight global_load_lds writes (the diagnosed ~900cyc/phase
//    stall). Ordering is manual: lgkmcnt(0) + sched_barrier(0) (rule #18).
//  * staging of tile s+2 moved to AFTER ph3's closing barrier (all waves'
//    reads of that buffer provably drained -> race-free) followed by vmcnt(8)
//    (waits only for tile s+1 => one full tile of latency cover) + barrier.
//    Pipe never drains to 0 in the main loop.

#define SA_(BUF, COL)                                                              \
  { char* d_ = smb + (BUF) * 65536 + stg;                                          \
    gload_lds16(pa + (COL),                     (unsigned short*)(d_));            \
    gload_lds16(pa + (COL) + (size_t)8 * Kv,    (unsigned short*)(d_ + 1024));     \
    gload_lds16(pa + (COL) + (size_t)128 * Kv,  (unsigned short*)(d_ + 16384));    \
    gload_lds16(pa + (COL) + (size_t)136 * Kv,  (unsigned short*)(d_ + 17408)); }

#define SB_(BUF, COL)                                                              \
  { char* d_ = smb + (BUF) * 65536 + 32768 + stg;                                  \
    gload_lds16(pb + (COL),                     (unsigned short*)(d_));            \
    gload_lds16(pb + (COL) + (size_t)8 * Kv,    (unsigned short*)(d_ + 1024));     \
    gload_lds16(pb + (COL) + (size_t)128 * Kv,  (unsigned short*)(d_ + 16384));    \
    gload_lds16(pb + (COL) + (size_t)136 * Kv,  (unsigned short*)(d_ + 17408)); }

#define RD_A(QM, G0)                                                               \
  _Pragma("unroll") for (int m_ = 0; m_ < 4; ++m_) {                               \
    const int ra_ = (QM) * 64 + m_ * 16 + l16;                                     \
    asm volatile("ds_read_b128 %0, %1" : "=v"(av[m_])                              \
                 : "v"(lds3 + aRd + ra_ * 128 + (((G0) ^ (ra_ & 7)) * 16)));       \
  }

#define RD_B(G0)                                                                   \
  _Pragma("unroll") for (int n_ = 0; n_ < 4; ++n_) {                               \
    const int rn_ = (wc & 1) * 64 + n_ * 16 + l16;                                 \
    asm volatile("ds_read_b128 %0, %1" : "=v"(bv[n_])                              \
                 : "v"(lds3 + bRd + rn_ * 128 + (((G0) ^ (rn_ & 7)) * 16)));       \
  }

#define MFMA16(QM)                                                                 \
  _Pragma("unroll") for (int n_ = 0; n_ < 4; ++n_)                                 \
    _Pragma("unroll") for (int m_ = 0; m_ < 4; ++m_)                               \
      acc[(QM)*4 + m_][n_] = __builtin_amdgcn_mfma_f32_16x16x32_bf16(              \
          av[m_], bv[n_], acc[(QM)*4 + m_][n_], 0, 0, 0);

#define PH_BODY(QM)                                                                \
  __builtin_amdgcn_s_barrier();                                                    \
  asm volatile("s_waitcnt lgkmcnt(0)" ::: "memory");                               \
  __builtin_amdgcn_sched_barrier(0);                                               \
  __builtin_amdgcn_s_setprio(1);                                                   \
  MFMA16(QM)                                                                       \
  __builtin_amdgcn_s_setprio(0);                                                   \
  __builtin_amdgcn_s_barrier();

#define TILE_(RB, STAGE_CODE, WAIT_CODE)                                           \
  { const int aRd = (RB) * 65536 + wr * 16384;                                     \
    const int bRd = (RB) * 65536 + 32768 + (wc >> 1) * 16384;                      \
    RD_A(0, quad) RD_B(quad)                                                       \
    PH_BODY(0)                                                                     \
    RD_A(1, quad)                                                                  \
    PH_BODY(1)                                                                     \
    RD_A(0, 4 + quad) RD_B(4 + quad)                                               \
    PH_BODY(0)                                                                     \
    RD_A(1, 4 + quad)                                                              \
    PH_BODY(1)                                                                     \
    STAGE_CODE      /* tile s+2 into buf[s&1]: reads drained by ph3 barrier */     \
    WAIT_CODE       /* vmcnt(8): waits only tile s+1 (full-tile cover) */          \
    __builtin_amdgcn_s_barrier(); }

template <int Mv, int Nv, int Kv>
__global__ __launch_bounds__(512, 2) void k_gemm256(const unsigned short* __restrict__ A,
                                                    const unsigned short* __restrict__ Bt,
                                                    unsigned short* __restrict__ C) {
  constexpr int NT = Kv / 64;
  constexpr int MTt = Mv / 256;        // 32 M-tiles
  constexpr int NTt = Nv / 256;        // 13 N-tiles
  constexpr int NWG = MTt * NTt;       // 416
  constexpr int STRIP = 4;             // M-tiles per XCD strip
  static_assert(NWG % 8 == 0, "grid must be divisible by 8 for the XCD swizzle");
  static_assert(MTt % STRIP == 0 && STRIP * NTt == NWG / 8,
                "strip partition must give exactly one strip per XCD");
  __shared__ __align__(16) char smb[131072];
  const __attribute__((address_space(3))) char* lds3 =
      (const __attribute__((address_space(3))) char*)smb;

  const int tid  = threadIdx.x;
  const int lane = tid & 63;
  const int wv   = tid >> 6;          // 0..7
  const int wr   = wv >> 2;           // 0..1 (M half)
  const int wc   = wv & 3;            // 0..3 (N quarter)
  const int quad = lane >> 4, l16 = lane & 15;

  // strip-partitioned XCD swizzle: XCD x gets tile-ids [x*52, (x+1)*52),
  // covering M-tiles [4x, 4x+4) x N-tiles [0,13), M-fastest.
  const int g   = blockIdx.x;
  const int lin = (g & 7) * (NWG / 8) + (g >> 3);
  const int bm0 = ((lin / (STRIP * NTt)) * STRIP + (lin & (STRIP - 1))) * 256;
  const int bn0 = ((lin % (STRIP * NTt)) / STRIP) * 256;

  // staging source (lane-swizzled 16B column groups; LDS dest stays linear)
  const int srow = lane >> 3;                 // 0..7 (== row & 7)
  const int scol = ((lane & 7) ^ srow) * 8;
  const unsigned short* pa = A  + (size_t)(bm0 + wv * 16 + srow) * Kv + scol;
  const unsigned short* pb = Bt + (size_t)(bn0 + wv * 16 + srow) * Kv + scol;
  const unsigned stg = (unsigned)(wv * 2048); // wave's 2KB chunk within a 16KB half

  bf16x8 av[4], bv[4];
  f32x4 acc[8][4] = {};

  // prologue: tiles 0 and 1 staged; vmcnt(8) => tile 0 landed, tile 1 in flight
  SA_(0, 0)  SB_(0, 0)
  SA_(1, 64) SB_(1, 64)
  asm volatile("s_waitcnt vmcnt(8)" ::: "memory");
  __builtin_amdgcn_s_barrier();

  size_t col = 128;   // column of tile s+2, staged at end of tile s
#pragma unroll 2
  for (int s = 0; s < NT - 2; ++s) {
    const int rb = s & 1;
    TILE_(rb,
          SA_(rb, col) SB_(rb, col),
          asm volatile("s_waitcnt vmcnt(8)" ::: "memory");)
    col += 64;
  }
  // tile NT-2: nothing left to stage; drain tile NT-1's loads
  TILE_(((NT - 2) & 1), , asm volatile("s_waitcnt vmcnt(0)" ::: "memory");)
  // tile NT-1: compute only
  TILE_(((NT - 1) & 1), , )

  // epilogue
#pragma unroll
  for (int mi = 0; mi < 8; ++mi) {
    const int row0 = bm0 + wr * 128 + mi * 16 + quad * 4;
#pragma unroll
    for (int n = 0; n < 4; ++n) {
      const int col2 = bn0 + wc * 64 + n * 16 + l16;
#pragma unroll
      for (int r = 0; r < 4; ++r)
        C[(size_t)(row0 + r) * Nv + col2] = f2bf(acc[mi][n][r]);
    }
  }
}

// ---------------- phase 1 (MFMA): gate MLP + cumsum + intra-chunk attention ----------------
// One block per (chunk, b, h). All matmuls via mfma_f32_16x16x32_bf16.
// LDS overlay (34,432 B -> 4 blocks/CU):
//   pre-barrier  [0,14976): SGLOW | SW2 | SBGK | VN      (dead after MLP-in + v-transpose)
//   post-barrier [0,14976): QEA | KEB | KET | EBL        (written only after the mid barrier)
//   static: QN | KN (AL overlays them after repack), VT.

#define P1_SGLOW 0         // 64 x 16 bf16            (2048)  [dead after gl unpack]
#define P1_SW2   2048      // 16 x 32 f32             (2048)  [dead after s]
#define P1_SBGK  4096      // 32 f32 (+pad)           (128)   [dead after s]
#define P1_VN    4224      // 64 x 72 bf16            (9216)  [dead after v-transpose]
#define P1_QEA   0         // 64 x 40 bf16 (qe)       (5120)  [post-barrier overlay]
#define P1_KEB   5120      // 64 x 40 bf16 (ke2)      (5120)  [post-barrier overlay]
#define P1_KET   10240     // 32 x 72 bf16 (ke2^T)    (4608)  [post-barrier overlay]
#define P1_EBL   14848     // 32 f32                  (128)   [post-barrier overlay]
#define P1_QN    14976     // 64 x 40 bf16            (5120)
#define P1_KN    20096     // 64 x 40 bf16            (5120)
#define P1_AL    P1_QN     // 64 x 72 bf16 overlay on q_n+k_n (9216 <= 10240)
#define P1_VT    25216     // 64 x 72 bf16 (v^T)      (9216)
#define P1_SIZE  34432

__global__ __launch_bounds__(256, 4) void k_phase1(unsigned short* __restrict__ pbuf,
                                                   const float* __restrict__ Wgk2,
                                                   const float* __restrict__ bgk,
                                                   unsigned short* __restrict__ obuf,
                                                   unsigned short* __restrict__ Ut,
                                                   float* __restrict__ dvec) {
  const int bi = blockIdx.x;
  const int c = bi >> 5, bh = bi & 31;
  const int b = bh >> 4, h = bh & 15;
  const int tid = threadIdx.x;
  const int lane = tid & 63, w = tid >> 6;
  const int quad = lane >> 4, l16 = lane & 15;

  __shared__ __align__(16) char sm[P1_SIZE];

  const size_t row0 = (size_t)(b * T_ + c * 64);
  const size_t rq  = row0 * NF_ + Q0_ + h * 32;
  const size_t rk  = row0 * NF_ + K0_ + h * 32;
  const size_t rv  = row0 * NF_ + V0_ + h * 64;
  const size_t rgl = row0 * NF_ + GL0_;
  const size_t cb  = (size_t)c * 32 + bh;

  // ---- staging (coalesced uint4) ----
  {
    int i = tid >> 2, seg = tid & 3;
    uint4 qu = *(const uint4*)(pbuf + rq + (size_t)i * NF_ + seg * 8);
    uint4 ku = *(const uint4*)(pbuf + rk + (size_t)i * NF_ + seg * 8);
    *(uint4*)(sm + P1_QN + i * 80 + seg * 16) = qu;
    *(uint4*)(sm + P1_KN + i * 80 + seg * 16) = ku;
  }
#pragma unroll
  for (int s = 0; s < 2; ++s) {
    int e = tid + s * 256;
    int j = e >> 3, seg = e & 7;
    uint4 vu = *(const uint4*)(pbuf + rv + (size_t)j * NF_ + seg * 8);
    *(uint4*)(sm + P1_VN + j * 144 + seg * 16) = vu;
  }
  if (tid < 128) {
    int i = tid >> 1, seg = tid & 1;
    uint4 gu = *(const uint4*)(pbuf + rgl + (size_t)i * NF_ + seg * 8);
    *(uint4*)(sm + P1_SGLOW + i * 32 + seg * 16) = gu;
    int r = tid >> 3, d4 = (tid & 7) * 4;
    *(float4*)(sm + P1_SW2 + (r * 32 + d4) * 4) = *(const float4*)(Wgk2 + r * KD_ + h * 32 + d4);
  }
  if (tid < 8)
    *(float4*)(sm + P1_SBGK + tid * 16) = *(const float4*)(bgk + h * 32 + tid * 4);
  __syncthreads();

  // ---- v transpose: v_n[j][vd] -> v_t[vd][j] (VN dead afterwards) ----
  {
    int vd = tid & 63, jg = tid >> 6;
#pragma unroll
    for (int half = 0; half < 2; ++half) {
      int j0 = jg * 8 + half * 32;
      unsigned short t8[8];
#pragma unroll
      for (int jj = 0; jj < 8; ++jj)
        t8[jj] = *(const unsigned short*)(sm + P1_VN + (j0 + jj) * 144 + vd * 2);
      *(uint4*)(sm + P1_VT + vd * 144 + j0 * 2) = pack8(t8);
    }
  }

  // ---- gate MLP + cumsum + qe/ke2 repack (thread: i=lane, 8 d's = wave*8..) ----
  {
    const int i = lane, dg = w;
    float gl[16];
    unpack8(*(const uint4*)(sm + P1_SGLOW + i * 32), gl);
    unpack8(*(const uint4*)(sm + P1_SGLOW + i * 32 + 16), gl + 8);
    float s[8];
    {
      float4 b0 = *(const float4*)(sm + P1_SBGK + dg * 32);
      float4 b1 = *(const float4*)(sm + P1_SBGK + dg * 32 + 16);
      s[0] = b0.x; s[1] = b0.y; s[2] = b0.z; s[3] = b0.w;
      s[4] = b1.x; s[5] = b1.y; s[6] = b1.z; s[7] = b1.w;
    }
#pragma unroll
    for (int r = 0; r < 16; ++r) {
      float4 wa = *(const float4*)(sm + P1_SW2 + (r * 32 + dg * 8) * 4);
      float4 wb = *(const float4*)(sm + P1_SW2 + (r * 32 + dg * 8) * 4 + 16);
      float gv = gl[r];
      s[0] += gv * wa.x; s[1] += gv * wa.y; s[2] += gv * wa.z; s[3] += gv * wa.w;
      s[4] += gv * wb.x; s[5] += gv * wb.y; s[6] += gv * wb.z; s[7] += gv * wb.w;
    }
    float bb[8];
#pragma unroll
    for (int j = 0; j < 8; ++j) {
      float ls = fminf(s[j], 0.0f) - __logf(1.0f + __expf(-fabsf(s[j])));
      float v = ls * GNORM_INV_;
#pragma unroll
      for (int off = 1; off < 64; off <<= 1) {
        int src = lane - off;
        float t2 = __shfl(v, src < 0 ? 0 : src, 64);
        if (lane >= off) v += t2;
      }
      bb[j] = v;
    }

    // mid barrier: SGLOW/SW2/SBGK consumed, VN transposed -> region [0,14976)
    // is now free for QEA/KEB/KET/EBL. (QN/KN still live: read below.)
    __syncthreads();

    if (lane == 63) {
      float ev[8];
#pragma unroll
      for (int j = 0; j < 8; ++j) {
        ev[j] = __expf(bb[j]);
        ((float*)(sm + P1_EBL))[dg * 8 + j] = ev[j];
      }
      float4 e0; e0.x = ev[0]; e0.y = ev[1]; e0.z = ev[2]; e0.w = ev[3];
      float4 e1; e1.x = ev[4]; e1.y = ev[5]; e1.z = ev[6]; e1.w = ev[7];
      *(float4*)(dvec + cb * 32 + dg * 8)     = e0;
      *(float4*)(dvec + cb * 32 + dg * 8 + 4) = e1;
    }
    float qf[8], kf[8];
    unpack8(*(const uint4*)(sm + P1_QN + i * 80 + dg * 16), qf);
    unpack8(*(const uint4*)(sm + P1_KN + i * 80 + dg * 16), kf);
    unsigned short qo[8], ko[8];
#pragma unroll
    for (int j = 0; j < 8; ++j) {
      float eb = __expf(bb[j]);
      float ie = __expf(-bb[j]);
      qo[j] = f2bf(qf[j] * eb * SCALE_);
      ko[j] = f2bf(kf[j] * ie);
      *(unsigned short*)(sm + P1_KET + (dg * 8 + j) * 144 + i * 2) = ko[j];
    }
    *(uint4*)(sm + P1_QEA + i * 80 + dg * 16) = pack8(qo);
    *(uint4*)(sm + P1_KEB + i * 80 + dg * 16) = pack8(ko);
  }
  __syncthreads();

  // ---- qe writeback to pbuf (for phase 3) ----
  {
    int i = tid >> 2, seg = tid & 3;
    *(uint4*)(pbuf + rq + (size_t)i * NF_ + seg * 8) =
        *(const uint4*)(sm + P1_QEA + i * 80 + seg * 16);
  }

  // ---- QK^T: A_s = qe . ke2^T (4 MFMA/wave) ----
  const int tm = w;
  bf16x8 aq = *(const bf16x8*)(sm + P1_QEA + (tm * 16 + l16) * 80 + quad * 16);
  f32x4 cA[4] = {};
#pragma unroll
  for (int tn = 0; tn < 4; ++tn) {
    bf16x8 bk = *(const bf16x8*)(sm + P1_KEB + (tn * 16 + l16) * 80 + quad * 16);
    cA[tn] = __builtin_amdgcn_mfma_f32_16x16x32_bf16(aq, bk, cA[tn], 0, 0, 0);
  }

  // ---- U = ke2^T . v, scaled by exp(b_last) -> Ut[vd][d] (4 MFMA/wave) ----
  {
    const int um = w >> 1;
    bf16x8 ak0 = *(const bf16x8*)(sm + P1_KET + (um * 16 + l16) * 144 + quad * 16);
    bf16x8 ak1 = *(const bf16x8*)(sm + P1_KET + (um * 16 + l16) * 144 + quad * 16 + 64);
    f32x4 cU[2] = {};
#pragma unroll
    for (int e = 0; e < 2; ++e) {
      int un = (w & 1) * 2 + e;
      bf16x8 bv0 = *(const bf16x8*)(sm + P1_VT + (un * 16 + l16) * 144 + quad * 16);
      bf16x8 bv1 = *(const bf16x8*)(sm + P1_VT + (un * 16 + l16) * 144 + quad * 16 + 64);
      cU[e] = __builtin_amdgcn_mfma_f32_16x16x32_bf16(ak0, bv0, cU[e], 0, 0, 0);
      cU[e] = __builtin_amdgcn_mfma_f32_16x16x32_bf16(ak1, bv1, cU[e], 0, 0, 0);
    }
    const int d0 = um * 16 + quad * 4;
    const float eb0 = ((const float*)(sm + P1_EBL))[d0];
    const float eb1 = ((const float*)(sm + P1_EBL))[d0 + 1];
    const float eb2 = ((const float*)(sm + P1_EBL))[d0 + 2];
    const float eb3 = ((const float*)(sm + P1_EBL))[d0 + 3];
#pragma unroll
    for (int e = 0; e < 2; ++e) {
      int un = (w & 1) * 2 + e;
      int vd = un * 16 + l16;
      unsigned long long u =
          (unsigned long long)((unsigned int)f2bf(cU[e][0] * eb0) |
                               ((unsigned int)f2bf(cU[e][1] * eb1) << 16)) |
          ((unsigned long long)((unsigned int)f2bf(cU[e][2] * eb2) |
                                ((unsigned int)f2bf(cU[e][3] * eb3) << 16)) << 32);
      *(unsigned long long*)(Ut + cb * 2048 + (size_t)vd * 32 + d0) = u;
    }
  }

  // ---- mask A_s (tril) -> A_l bf16 (overlay on q_n/k_n: dead after repack) ----
#pragma unroll
  for (int tn = 0; tn < 4; ++tn)
#pragma unroll
    for (int r = 0; r < 4; ++r) {
      int row = tm * 16 + quad * 4 + r;
      int col = tn * 16 + l16;
      float av2 = (col <= row) ? cA[tn][r] : 0.0f;
      *(unsigned short*)(sm + P1_AL + row * 144 + col * 2) = f2bf(av2);
    }
  __syncthreads();

  // ---- o_intra = A_s . v -> obuf raw fragment order (8 MFMA/wave) ----
  {
    bf16x8 aA0 = *(const bf16x8*)(sm + P1_AL + (tm * 16 + l16) * 144 + quad * 16);
    bf16x8 aA1 = *(const bf16x8*)(sm + P1_AL + (tm * 16 + l16) * 144 + quad * 16 + 64);
    unsigned short ob[16];
#pragma unroll
    for (int tn = 0; tn < 4; ++tn) {
      bf16x8 bv0 = *(const bf16x8*)(sm + P1_VT + (tn * 16 + l16) * 144 + quad * 16);
      bf16x8 bv1 = *(const bf16x8*)(sm + P1_VT + (tn * 16 + l16) * 144 + quad * 16 + 64);
      f32x4 co = {};
      co = __builtin_amdgcn_mfma_f32_16x16x32_bf16(aA0, bv0, co, 0, 0, 0);
      co = __builtin_amdgcn_mfma_f32_16x16x32_bf16(aA1, bv1, co, 0, 0, 0);
#pragma unroll
      for (int r = 0; r < 4; ++r)
        ob[tn * 4 + r] = f2bf(co[r]);
    }
    *(uint4*)(obuf + cb * 4096 + tid * 16)     = pack8(ob);
    *(uint4*)(obuf + cb * 4096 + tid * 16 + 8) = pack8(ob + 8);
  }
}

// ---------------- phase 2: inter-chunk state recurrence (coalesced on [vd][d]) ----------------

__global__ __launch_bounds__(128) void k_phase2(const unsigned short* __restrict__ Ut,
                                                const float* __restrict__ dvec,
                                                unsigned short* __restrict__ Sp) {
  int idx = blockIdx.x * 128 + threadIdx.x;   // 32768
  int bh = idx >> 10, q = idx & 1023;
  int vd = q >> 4, d2 = (q & 15) * 2;
  float run0 = 0.0f, run1 = 0.0f;
  for (int c = 0; c < NC_; ++c) {
    size_t o = ((size_t)c * 32 + bh) * 2048 + vd * 32 + d2;
    unsigned int uu = *(const unsigned int*)(Ut + o);
    *(unsigned int*)(Sp + o) =
        (unsigned int)f2bf(run0) | ((unsigned int)f2bf(run1) << 16);
    float2 dv = *(const float2*)(dvec + ((size_t)c * 32 + bh) * 32 + d2);
    run0 = dv.x * run0 + bf2f(uu & 0xffff);
    run1 = dv.y * run1 + bf2f(uu >> 16);
  }
}

// ---------------- phase 3 (MFMA): o = o_intra + qe.S, fused RMS/swish -> ybuf ----------------

#define P3_QEA 0          // 64 x 40 bf16  (5120)
#define P3_SL  5120       // 64 x 40 bf16 (S rows vd, 32 d each) (5120)
#define P3_OL  10240      // 64 x 68 f32   (17408)
#define P3_SIZE 27648

__global__ __launch_bounds__(256) void k_phase3rms(const unsigned short* __restrict__ pbuf,
                                                   const unsigned short* __restrict__ obuf,
                                                   const unsigned short* __restrict__ Sp,
                                                   const float* __restrict__ norm_w,
                                                   unsigned short* __restrict__ ybuf) {
  const int bi = blockIdx.x;
  const int c = bi >> 5, bh = bi & 31;
  const int b = bh >> 4, h = bh & 15;
  const int tid = threadIdx.x;
  const int lane = tid & 63, w = tid >> 6;
  const int quad = lane >> 4, l16 = lane & 15;

  __shared__ __align__(16) char sm[P3_SIZE];

  const size_t row0 = (size_t)(b * T_ + c * 64);
  const size_t rq = row0 * NF_ + Q0_ + h * 32;
  const size_t cb = (size_t)c * 32 + bh;

  {
    int i = tid >> 2, seg = tid & 3;
    *(uint4*)(sm + P3_QEA + i * 80 + seg * 16) =
        *(const uint4*)(pbuf + rq + (size_t)i * NF_ + seg * 8);
    *(uint4*)(sm + P3_SL + i * 80 + seg * 16) =
        *(const uint4*)(Sp + cb * 2048 + (size_t)i * 32 + seg * 8);
  }

  // o_intra fragment load (coalesced, overlaps LDS staging latency)
  float obf[16];
  {
    uint4 o0 = *(const uint4*)(obuf + cb * 4096 + tid * 16);
    uint4 o1 = *(const uint4*)(obuf + cb * 4096 + tid * 16 + 8);
    unpack8(o0, obf);
    unpack8(o1, obf + 8);
  }
  __syncthreads();

  const int tm = w;
  bf16x8 aq = *(const bf16x8*)(sm + P3_QEA + (tm * 16 + l16) * 80 + quad * 16);
#pragma unroll
  for (int tn = 0; tn < 4; ++tn) {
    bf16x8 bs = *(const bf16x8*)(sm + P3_SL + (tn * 16 + l16) * 80 + quad * 16);
    f32x4 co = {};
    co = __builtin_amdgcn_mfma_f32_16x16x32_bf16(aq, bs, co, 0, 0, 0);
#pragma unroll
    for (int r = 0; r < 4; ++r) {
      int row = tm * 16 + quad * 4 + r;
      int col = tn * 16 + l16;
      float o = co[r] + obf[tn * 4 + r];
      *(float*)(sm + P3_OL + (row * 68 + col) * 4) = o;
    }
  }
  __syncthreads();

  // RMS + swish: thread = (2 rows, 8 vd each)
  {
    int r0 = tid >> 3, s8 = tid & 7;
#pragma unroll
    for (int half = 0; half < 2; ++half) {
      int row = r0 + half * 32;
      float4 a  = *(const float4*)(sm + P3_OL + (row * 68 + s8 * 8) * 4);
      float4 b4 = *(const float4*)(sm + P3_OL + (row * 68 + s8 * 8) * 4 + 16);
      float p = a.x*a.x + a.y*a.y + a.z*a.z + a.w*a.w
              + b4.x*b4.x + b4.y*b4.y + b4.z*b4.z + b4.w*b4.w;
      p += __shfl_xor(p, 1, 64);
      p += __shfl_xor(p, 2, 64);
      p += __shfl_xor(p, 4, 64);
      float rs = rsqrtf(p * (1.0f / 64.0f) + EPS_);
      size_t m = row0 + row;
      float gv[8];
      unpack8(*(const uint4*)(pbuf + m * NF_ + G0_ + h * 64 + s8 * 8), gv);
      float4 n0 = *(const float4*)(norm_w + s8 * 8);
      float4 n1 = *(const float4*)(norm_w + s8 * 8 + 4);
      float nw[8] = {n0.x, n0.y, n0.z, n0.w, n1.x, n1.y, n1.z, n1.w};
      float ov[8] = {a.x, a.y, a.z, a.w, b4.x, b4.y, b4.z, b4.w};
      unsigned short yo[8];
#pragma unroll
      for (int j = 0; j < 8; ++j) {
        float sw = gv[j] / (1.0f + __expf(-gv[j]));
        yo[j] = f2bf(ov[j] * rs * nw[j] * sw);
      }
      *(uint4*)(ybuf + m * VD_ + h * 64 + s8 * 8) = pack8(yo);
    }
  }
}

// ---------------- launch ----------------

extern "C" void kernel_launch(void* const* d_in, const int* in_sizes, int n_in,
                              void* d_out, int out_size, void* d_ws, size_t ws_size,
                              hipStream_t stream) {
  const float* x    = (const float*)d_in[0];
  const float* Wq   = (const float*)d_in[1];
  const float* Wk   = (const float*)d_in[2];
  const float* Wv   = (const float*)d_in[3];
  const float* Wgk1 = (const float*)d_in[4];
  const float* Wgk2 = (const float*)d_in[5];
  const float* bgk  = (const float*)d_in[6];
  const float* Wg   = (const float*)d_in[7];
  const float* nw   = (const float*)d_in[8];
  const float* Wo   = (const float*)d_in[9];
  float* out = (float*)d_out;

  char* p = (char*)d_ws;
  unsigned short* xb   = (unsigned short*)p;  p += (size_t)M_ * D_ * 2;
  unsigned short* Wcat = (unsigned short*)p;  p += (size_t)NF_ * D_ * 2;
  unsigned short* woT  = (unsigned short*)p;  p += (size_t)D_ * VD_ * 2;
  unsigned short* pbuf = (unsigned short*)p;  p += (size_t)M_ * NF_ * 2;
  unsigned short* obuf = (unsigned short*)p;  p += (size_t)M_ * VD_ * 2;
  unsigned short* Ubuf = (unsigned short*)p;  p += (size_t)NC_ * 32 * 2048 * 2;
  unsigned short* Sbuf = (unsigned short*)p;  p += (size_t)NC_ * 32 * 2048 * 2;
  float* dbuf = (float*)p;                    p += (size_t)NC_ * 32 * 32 * 4;
  unsigned short* ybuf = (unsigned short*)p;  p += (size_t)M_ * VD_ * 2;

  // zero the 128 pad rows of Wcat (cols [3200,3328) of the fused projection)
  hipMemsetAsync(Wcat + (size_t)NVALID_ * D_, 0, (size_t)(NF_ - NVALID_) * D_ * 2, stream);

  // prep: all weight transposes + x f32->bf16 in one launch
  k_prep<<<dim3(32, 32, 14), 256, 0, stream>>>(x, Wq, Wk, Wv, Wg, Wo, Wgk1, xb, Wcat, woT);

  // fused projections: q|k|v|g|glow|pad in one 256^2 GEMM (bf16 out)
  k_gemm256<M_, NF_, D_><<<(M_ / 256) * (NF_ / 256), 512, 0, stream>>>(xb, Wcat, pbuf);

  // attention (all matmuls MFMA)
  k_phase1<<<NC_ * 32, 256, 0, stream>>>(pbuf, Wgk2, bgk, obuf, Ubuf, dbuf);
  k_phase2<<<256, 128, 0, stream>>>(Ubuf, dbuf, Sbuf);
  k_phase3rms<<<NC_ * 32, 256, 0, stream>>>(pbuf, obuf, Sbuf, nw, ybuf);

  // output projection (f32 out), 128^2 kernel (full-chip at 512 blocks)
  k_gemm_bt<float><<<(D_/128) * (M_/128), 256, 0, stream>>>(ybuf, woT, out, M_, D_, VD_);
}

// Round 6
// 234.243 us; speedup vs baseline: 1.0436x; 1.0436x over previous
//
#include <hip/hip_runtime.h>
#include <cstddef>

#define B_   2
#define T_   4096
#define D_   1024
#define H_   16
#define KD_  512
#define VD_  1024
#define NC_  64          // T/CHUNK
#define M_   (B_*T_)     // 8192
#define GR_  16
#define EPS_ 1e-5f
#define SCALE_ 0.17677669529663687f  // 32^-0.5
#define GNORM_INV_ (1.0f/16.0f)

// fused projection layout: cols [0,512)=q, [512,1024)=k, [1024,2048)=v,
// [2048,3072)=g, [3072,3200)=glow (only first 16 weight rows nonzero)
#define NF_   3200
#define Q0_   0
#define K0_   512
#define V0_   1024
#define G0_   2048
#define GL0_  3072

typedef __attribute__((ext_vector_type(8))) __bf16 bf16x8;
typedef __attribute__((ext_vector_type(4))) float f32x4;

__device__ inline unsigned short f2bf(float f) {
  unsigned int u = __float_as_uint(f);
  u = (u + 0x7fffu + ((u >> 16) & 1u)) >> 16;
  return (unsigned short)u;
}
__device__ inline float bf2f(unsigned short u) {
  return __uint_as_float((unsigned int)u << 16);
}
__device__ inline void unpack8(uint4 u, float* f) {
  f[0] = bf2f(u.x & 0xffff); f[1] = bf2f(u.x >> 16);
  f[2] = bf2f(u.y & 0xffff); f[3] = bf2f(u.y >> 16);
  f[4] = bf2f(u.z & 0xffff); f[5] = bf2f(u.z >> 16);
  f[6] = bf2f(u.w & 0xffff); f[7] = bf2f(u.w >> 16);
}
__device__ inline uint4 pack8(const unsigned short* s) {
  uint4 u;
  u.x = (unsigned int)s[0] | ((unsigned int)s[1] << 16);
  u.y = (unsigned int)s[2] | ((unsigned int)s[3] << 16);
  u.z = (unsigned int)s[4] | ((unsigned int)s[5] << 16);
  u.w = (unsigned int)s[6] | ((unsigned int)s[7] << 16);
  return u;
}

__device__ __forceinline__ void gload_lds16(const unsigned short* g, unsigned short* l) {
  __builtin_amdgcn_global_load_lds(
      (const __attribute__((address_space(1))) unsigned int*)g,
      (__attribute__((address_space(3))) unsigned int*)l, 16, 0, 0);
}

// ---------------- prep: weight transposes (+Wgk1 pad) AND x f32->bf16, one launch ----------------

__global__ __launch_bounds__(256) void k_prep(const float* __restrict__ x,
                                              const float* __restrict__ Wq,
                                              const float* __restrict__ Wk,
                                              const float* __restrict__ Wv,
                                              const float* __restrict__ Wg,
                                              const float* __restrict__ Wo,
                                              const float* __restrict__ Wgk1,
                                              unsigned short* __restrict__ xb,
                                              unsigned short* __restrict__ Wcat,
                                              unsigned short* __restrict__ woT) {
  __shared__ float tile[32][33];
  if (blockIdx.z >= 6) {
    int lin = ((blockIdx.z - 6) * 1024 + blockIdx.y * 32 + blockIdx.x) * 256 + threadIdx.x;
    int i = lin * 4;
    float4 f = *(const float4*)(x + i);
    ushort4 o;
    o.x = f2bf(f.x); o.y = f2bf(f.y); o.z = f2bf(f.z); o.w = f2bf(f.w);
    *(ushort4*)(xb + i) = o;
    return;
  }
  const float* in; unsigned short* out; int N;
  switch (blockIdx.z) {
    case 0: in = Wq;   out = Wcat + (size_t)Q0_ * D_;  N = 512;  break;
    case 1: in = Wk;   out = Wcat + (size_t)K0_ * D_;  N = 512;  break;
    case 2: in = Wv;   out = Wcat + (size_t)V0_ * D_;  N = 1024; break;
    case 3: in = Wg;   out = Wcat + (size_t)G0_ * D_;  N = 1024; break;
    case 4: in = Wo;   out = woT;                      N = 1024; break;
    default: in = Wgk1; out = Wcat + (size_t)GL0_ * D_; N = 128;  break;  // pad: cols >= 16 are 0
  }
  int n0 = blockIdx.x * 32, k0 = blockIdx.y * 32;
  if (n0 >= N) return;
  int tx = threadIdx.x & 31, ty = threadIdx.x >> 5;   // 32 x 8
  if (blockIdx.z == 5) {
#pragma unroll
    for (int p = 0; p < 4; ++p)
      tile[ty + p*8][tx] = (n0 + tx < GR_) ? in[(size_t)(k0 + ty + p*8) * GR_ + n0 + tx] : 0.0f;
  } else {
#pragma unroll
    for (int p = 0; p < 4; ++p)
      tile[ty + p*8][tx] = in[(size_t)(k0 + ty + p*8) * N + n0 + tx];
  }
  __syncthreads();
#pragma unroll
  for (int p = 0; p < 4; ++p)
    out[(size_t)(n0 + ty + p*8) * 1024 + k0 + tx] = f2bf(tile[tx][ty + p*8]);
}

// ---------------- bf16 MFMA GEMM: C(MxN) = A(MxK) * Bt(NxK)^T ----------------
// 128x128 tile, BK=64, 256 threads (4 waves 2x2), 16x16x32 MFMA.
// XCD-aware 1D swizzle; global_load_lds width=16 with source-column XOR swizzle.
// This is the session's GEMM plateau (m97-structure ceiling, ~900 TF): three
// 256^2 8-phase attempts (r1/r2/r5) all pinned at ~30% MfmaUtil -- abandoned.

template <typename OutT>
__global__ __launch_bounds__(256, 3) void k_gemm_bt(const unsigned short* __restrict__ A,
                                                    const unsigned short* __restrict__ Bt,
                                                    OutT* __restrict__ C,
                                                    int M, int N, int K) {
  __shared__ __align__(16) unsigned short sA[128 * 64];
  __shared__ __align__(16) unsigned short sB[128 * 64];
  const int tid  = threadIdx.x;
  const int lane = tid & 63;
  const int wave = tid >> 6;
  const int wr = wave >> 1, wc = wave & 1;
  const int quad = lane >> 4, l16 = lane & 15;

  const int g = blockIdx.x;
  const int xcd = g & 7, slot = g >> 3;
  const int bm0 = ((xcd << 3) | (slot & 7)) << 7;   // M-tile
  const int bn0 = (slot >> 3) << 7;                 // N-tile

  const int lrow = lane >> 3;                      // 0..7 (== row & 7)
  const int gcol = ((lane & 7) ^ lrow) * 8;        // swizzled source column
  const unsigned short* ga = A  + (size_t)(bm0 + wave * 8 + lrow) * K + gcol;
  const unsigned short* gb = Bt + (size_t)(bn0 + wave * 8 + lrow) * K + gcol;
  unsigned short* la = sA + wave * 8 * 64;
  unsigned short* lb = sB + wave * 8 * 64;

  f32x4 acc[4][4] = {};

  for (int k0 = 0; k0 < K; k0 += 64) {
#pragma unroll
    for (int it = 0; it < 4; ++it) {
      gload_lds16(ga + k0 + (size_t)it * 32 * K, la + it * 32 * 64);
      gload_lds16(gb + k0 + (size_t)it * 32 * K, lb + it * 32 * 64);
    }
    __syncthreads();
#pragma unroll
    for (int kk = 0; kk < 2; ++kk) {
      bf16x8 af[4], bfv[4];
#pragma unroll
      for (int i = 0; i < 4; ++i) {
        int row = wr * 64 + i * 16 + l16;
        int gg = (kk * 4 + quad) ^ (row & 7);
        af[i] = *(const bf16x8*)(sA + row * 64 + gg * 8);
      }
#pragma unroll
      for (int j = 0; j < 4; ++j) {
        int row = wc * 64 + j * 16 + l16;
        int gg = (kk * 4 + quad) ^ (row & 7);
        bfv[j] = *(const bf16x8*)(sB + row * 64 + gg * 8);
      }
#pragma unroll
      for (int i = 0; i < 4; ++i)
#pragma unroll
        for (int j = 0; j < 4; ++j)
          acc[i][j] = __builtin_amdgcn_mfma_f32_16x16x32_bf16(af[i], bfv[j], acc[i][j], 0, 0, 0);
    }
    __syncthreads();
  }

#pragma unroll
  for (int i = 0; i < 4; ++i) {
    int row0 = bm0 + wr * 64 + i * 16 + quad * 4;
#pragma unroll
    for (int j = 0; j < 4; ++j) {
      int col = bn0 + wc * 64 + j * 16 + l16;
#pragma unroll
      for (int r = 0; r < 4; ++r) {
        float v = acc[i][j][r];
        if constexpr (sizeof(OutT) == 2)
          C[(size_t)(row0 + r) * N + col] = (OutT)f2bf(v);
        else
          C[(size_t)(row0 + r) * N + col] = (OutT)v;
      }
    }
  }
}

// ---------------- phase 1 (MFMA): gate MLP + cumsum + intra-chunk attention ----------------
// One block per (chunk, b, h). All matmuls via mfma_f32_16x16x32_bf16.
// LDS overlay (34,432 B -> 4 blocks/CU):
//   pre-barrier  [0,14976): SGLOW | SW2 | SBGK | VN      (dead after MLP-in + v-transpose)
//   post-barrier [0,14976): QEA | KEB | KET | EBL        (written only after the mid barrier)
//   static: QN | KN (AL overlays them after repack), VT.

#define P1_SGLOW 0         // 64 x 16 bf16            (2048)  [dead after gl unpack]
#define P1_SW2   2048      // 16 x 32 f32             (2048)  [dead after s]
#define P1_SBGK  4096      // 32 f32 (+pad)           (128)   [dead after s]
#define P1_VN    4224      // 64 x 72 bf16            (9216)  [dead after v-transpose]
#define P1_QEA   0         // 64 x 40 bf16 (qe)       (5120)  [post-barrier overlay]
#define P1_KEB   5120      // 64 x 40 bf16 (ke2)      (5120)  [post-barrier overlay]
#define P1_KET   10240     // 32 x 72 bf16 (ke2^T)    (4608)  [post-barrier overlay]
#define P1_EBL   14848     // 32 f32                  (128)   [post-barrier overlay]
#define P1_QN    14976     // 64 x 40 bf16            (5120)
#define P1_KN    20096     // 64 x 40 bf16            (5120)
#define P1_AL    P1_QN     // 64 x 72 bf16 overlay on q_n+k_n (9216 <= 10240)
#define P1_VT    25216     // 64 x 72 bf16 (v^T)      (9216)
#define P1_SIZE  34432

__global__ __launch_bounds__(256, 4) void k_phase1(unsigned short* __restrict__ pbuf,
                                                   const float* __restrict__ Wgk2,
                                                   const float* __restrict__ bgk,
                                                   unsigned short* __restrict__ obuf,
                                                   unsigned short* __restrict__ Ut,
                                                   float* __restrict__ dvec) {
  const int bi = blockIdx.x;
  const int c = bi >> 5, bh = bi & 31;
  const int b = bh >> 4, h = bh & 15;
  const int tid = threadIdx.x;
  const int lane = tid & 63, w = tid >> 6;
  const int quad = lane >> 4, l16 = lane & 15;

  __shared__ __align__(16) char sm[P1_SIZE];

  const size_t row0 = (size_t)(b * T_ + c * 64);
  const size_t rq  = row0 * NF_ + Q0_ + h * 32;
  const size_t rk  = row0 * NF_ + K0_ + h * 32;
  const size_t rv  = row0 * NF_ + V0_ + h * 64;
  const size_t rgl = row0 * NF_ + GL0_;
  const size_t cb  = (size_t)c * 32 + bh;

  // ---- staging (coalesced uint4) ----
  {
    int i = tid >> 2, seg = tid & 3;
    uint4 qu = *(const uint4*)(pbuf + rq + (size_t)i * NF_ + seg * 8);
    uint4 ku = *(const uint4*)(pbuf + rk + (size_t)i * NF_ + seg * 8);
    *(uint4*)(sm + P1_QN + i * 80 + seg * 16) = qu;
    *(uint4*)(sm + P1_KN + i * 80 + seg * 16) = ku;
  }
#pragma unroll
  for (int s = 0; s < 2; ++s) {
    int e = tid + s * 256;
    int j = e >> 3, seg = e & 7;
    uint4 vu = *(const uint4*)(pbuf + rv + (size_t)j * NF_ + seg * 8);
    *(uint4*)(sm + P1_VN + j * 144 + seg * 16) = vu;
  }
  if (tid < 128) {
    int i = tid >> 1, seg = tid & 1;
    uint4 gu = *(const uint4*)(pbuf + rgl + (size_t)i * NF_ + seg * 8);
    *(uint4*)(sm + P1_SGLOW + i * 32 + seg * 16) = gu;
    int r = tid >> 3, d4 = (tid & 7) * 4;
    *(float4*)(sm + P1_SW2 + (r * 32 + d4) * 4) = *(const float4*)(Wgk2 + r * KD_ + h * 32 + d4);
  }
  if (tid < 8)
    *(float4*)(sm + P1_SBGK + tid * 16) = *(const float4*)(bgk + h * 32 + tid * 4);
  __syncthreads();

  // ---- v transpose: v_n[j][vd] -> v_t[vd][j] (VN dead afterwards) ----
  {
    int vd = tid & 63, jg = tid >> 6;
#pragma unroll
    for (int half = 0; half < 2; ++half) {
      int j0 = jg * 8 + half * 32;
      unsigned short t8[8];
#pragma unroll
      for (int jj = 0; jj < 8; ++jj)
        t8[jj] = *(const unsigned short*)(sm + P1_VN + (j0 + jj) * 144 + vd * 2);
      *(uint4*)(sm + P1_VT + vd * 144 + j0 * 2) = pack8(t8);
    }
  }

  // ---- gate MLP + cumsum + qe/ke2 repack (thread: i=lane, 8 d's = wave*8..) ----
  {
    const int i = lane, dg = w;
    float gl[16];
    unpack8(*(const uint4*)(sm + P1_SGLOW + i * 32), gl);
    unpack8(*(const uint4*)(sm + P1_SGLOW + i * 32 + 16), gl + 8);
    float s[8];
    {
      float4 b0 = *(const float4*)(sm + P1_SBGK + dg * 32);
      float4 b1 = *(const float4*)(sm + P1_SBGK + dg * 32 + 16);
      s[0] = b0.x; s[1] = b0.y; s[2] = b0.z; s[3] = b0.w;
      s[4] = b1.x; s[5] = b1.y; s[6] = b1.z; s[7] = b1.w;
    }
#pragma unroll
    for (int r = 0; r < 16; ++r) {
      float4 wa = *(const float4*)(sm + P1_SW2 + (r * 32 + dg * 8) * 4);
      float4 wb = *(const float4*)(sm + P1_SW2 + (r * 32 + dg * 8) * 4 + 16);
      float gv = gl[r];
      s[0] += gv * wa.x; s[1] += gv * wa.y; s[2] += gv * wa.z; s[3] += gv * wa.w;
      s[4] += gv * wb.x; s[5] += gv * wb.y; s[6] += gv * wb.z; s[7] += gv * wb.w;
    }
    float bb[8];
#pragma unroll
    for (int j = 0; j < 8; ++j) {
      float ls = fminf(s[j], 0.0f) - __logf(1.0f + __expf(-fabsf(s[j])));
      float v = ls * GNORM_INV_;
#pragma unroll
      for (int off = 1; off < 64; off <<= 1) {
        int src = lane - off;
        float t2 = __shfl(v, src < 0 ? 0 : src, 64);
        if (lane >= off) v += t2;
      }
      bb[j] = v;
    }

    // mid barrier: SGLOW/SW2/SBGK consumed, VN transposed -> region [0,14976)
    // is now free for QEA/KEB/KET/EBL. (QN/KN still live: read below.)
    __syncthreads();

    if (lane == 63) {
      float ev[8];
#pragma unroll
      for (int j = 0; j < 8; ++j) {
        ev[j] = __expf(bb[j]);
        ((float*)(sm + P1_EBL))[dg * 8 + j] = ev[j];
      }
      float4 e0; e0.x = ev[0]; e0.y = ev[1]; e0.z = ev[2]; e0.w = ev[3];
      float4 e1; e1.x = ev[4]; e1.y = ev[5]; e1.z = ev[6]; e1.w = ev[7];
      *(float4*)(dvec + cb * 32 + dg * 8)     = e0;
      *(float4*)(dvec + cb * 32 + dg * 8 + 4) = e1;
    }
    float qf[8], kf[8];
    unpack8(*(const uint4*)(sm + P1_QN + i * 80 + dg * 16), qf);
    unpack8(*(const uint4*)(sm + P1_KN + i * 80 + dg * 16), kf);
    unsigned short qo[8], ko[8];
#pragma unroll
    for (int j = 0; j < 8; ++j) {
      float eb = __expf(bb[j]);
      float ie = __expf(-bb[j]);
      qo[j] = f2bf(qf[j] * eb * SCALE_);
      ko[j] = f2bf(kf[j] * ie);
      *(unsigned short*)(sm + P1_KET + (dg * 8 + j) * 144 + i * 2) = ko[j];
    }
    *(uint4*)(sm + P1_QEA + i * 80 + dg * 16) = pack8(qo);
    *(uint4*)(sm + P1_KEB + i * 80 + dg * 16) = pack8(ko);
  }
  __syncthreads();

  // ---- qe writeback to pbuf (for phase 3) ----
  {
    int i = tid >> 2, seg = tid & 3;
    *(uint4*)(pbuf + rq + (size_t)i * NF_ + seg * 8) =
        *(const uint4*)(sm + P1_QEA + i * 80 + seg * 16);
  }

  // ---- QK^T: A_s = qe . ke2^T (4 MFMA/wave) ----
  const int tm = w;
  bf16x8 aq = *(const bf16x8*)(sm + P1_QEA + (tm * 16 + l16) * 80 + quad * 16);
  f32x4 cA[4] = {};
#pragma unroll
  for (int tn = 0; tn < 4; ++tn) {
    bf16x8 bk = *(const bf16x8*)(sm + P1_KEB + (tn * 16 + l16) * 80 + quad * 16);
    cA[tn] = __builtin_amdgcn_mfma_f32_16x16x32_bf16(aq, bk, cA[tn], 0, 0, 0);
  }

  // ---- U = ke2^T . v, scaled by exp(b_last) -> Ut[vd][d] (4 MFMA/wave) ----
  {
    const int um = w >> 1;
    bf16x8 ak0 = *(const bf16x8*)(sm + P1_KET + (um * 16 + l16) * 144 + quad * 16);
    bf16x8 ak1 = *(const bf16x8*)(sm + P1_KET + (um * 16 + l16) * 144 + quad * 16 + 64);
    f32x4 cU[2] = {};
#pragma unroll
    for (int e = 0; e < 2; ++e) {
      int un = (w & 1) * 2 + e;
      bf16x8 bv0 = *(const bf16x8*)(sm + P1_VT + (un * 16 + l16) * 144 + quad * 16);
      bf16x8 bv1 = *(const bf16x8*)(sm + P1_VT + (un * 16 + l16) * 144 + quad * 16 + 64);
      cU[e] = __builtin_amdgcn_mfma_f32_16x16x32_bf16(ak0, bv0, cU[e], 0, 0, 0);
      cU[e] = __builtin_amdgcn_mfma_f32_16x16x32_bf16(ak1, bv1, cU[e], 0, 0, 0);
    }
    const int d0 = um * 16 + quad * 4;
    const float eb0 = ((const float*)(sm + P1_EBL))[d0];
    const float eb1 = ((const float*)(sm + P1_EBL))[d0 + 1];
    const float eb2 = ((const float*)(sm + P1_EBL))[d0 + 2];
    const float eb3 = ((const float*)(sm + P1_EBL))[d0 + 3];
#pragma unroll
    for (int e = 0; e < 2; ++e) {
      int un = (w & 1) * 2 + e;
      int vd = un * 16 + l16;
      unsigned long long u =
          (unsigned long long)((unsigned int)f2bf(cU[e][0] * eb0) |
                               ((unsigned int)f2bf(cU[e][1] * eb1) << 16)) |
          ((unsigned long long)((unsigned int)f2bf(cU[e][2] * eb2) |
                                ((unsigned int)f2bf(cU[e][3] * eb3) << 16)) << 32);
      *(unsigned long long*)(Ut + cb * 2048 + (size_t)vd * 32 + d0) = u;
    }
  }

  // ---- mask A_s (tril) -> A_l bf16 (overlay on q_n/k_n: dead after repack) ----
#pragma unroll
  for (int tn = 0; tn < 4; ++tn)
#pragma unroll
    for (int r = 0; r < 4; ++r) {
      int row = tm * 16 + quad * 4 + r;
      int col = tn * 16 + l16;
      float av2 = (col <= row) ? cA[tn][r] : 0.0f;
      *(unsigned short*)(sm + P1_AL + row * 144 + col * 2) = f2bf(av2);
    }
  __syncthreads();

  // ---- o_intra = A_s . v -> obuf raw fragment order (8 MFMA/wave) ----
  {
    bf16x8 aA0 = *(const bf16x8*)(sm + P1_AL + (tm * 16 + l16) * 144 + quad * 16);
    bf16x8 aA1 = *(const bf16x8*)(sm + P1_AL + (tm * 16 + l16) * 144 + quad * 16 + 64);
    unsigned short ob[16];
#pragma unroll
    for (int tn = 0; tn < 4; ++tn) {
      bf16x8 bv0 = *(const bf16x8*)(sm + P1_VT + (tn * 16 + l16) * 144 + quad * 16);
      bf16x8 bv1 = *(const bf16x8*)(sm + P1_VT + (tn * 16 + l16) * 144 + quad * 16 + 64);
      f32x4 co = {};
      co = __builtin_amdgcn_mfma_f32_16x16x32_bf16(aA0, bv0, co, 0, 0, 0);
      co = __builtin_amdgcn_mfma_f32_16x16x32_bf16(aA1, bv1, co, 0, 0, 0);
#pragma unroll
      for (int r = 0; r < 4; ++r)
        ob[tn * 4 + r] = f2bf(co[r]);
    }
    *(uint4*)(obuf + cb * 4096 + tid * 16)     = pack8(ob);
    *(uint4*)(obuf + cb * 4096 + tid * 16 + 8) = pack8(ob + 8);
  }
}

// ---------------- phase 2: inter-chunk state recurrence (coalesced on [vd][d]) ----------------

__global__ __launch_bounds__(128) void k_phase2(const unsigned short* __restrict__ Ut,
                                                const float* __restrict__ dvec,
                                                unsigned short* __restrict__ Sp) {
  int idx = blockIdx.x * 128 + threadIdx.x;   // 32768
  int bh = idx >> 10, q = idx & 1023;
  int vd = q >> 4, d2 = (q & 15) * 2;
  float run0 = 0.0f, run1 = 0.0f;
  for (int c = 0; c < NC_; ++c) {
    size_t o = ((size_t)c * 32 + bh) * 2048 + vd * 32 + d2;
    unsigned int uu = *(const unsigned int*)(Ut + o);
    *(unsigned int*)(Sp + o) =
        (unsigned int)f2bf(run0) | ((unsigned int)f2bf(run1) << 16);
    float2 dv = *(const float2*)(dvec + ((size_t)c * 32 + bh) * 32 + d2);
    run0 = dv.x * run0 + bf2f(uu & 0xffff);
    run1 = dv.y * run1 + bf2f(uu >> 16);
  }
}

// ---------------- phase 3 v2 (MFMA): o = o_intra + qe.S, in-register RMS/swish -> ybuf ----------------
// Wave tm owns FULL rows tm*16..tm*16+16 (all 64 cols), so the RMS row-sum is
// in-register: sum over tn in-lane + 4x shfl_xor(1,2,4,8) across the 16-lane
// group. Kills the 17.4 KB f32 OL buffer, its LDS round-trip, and a barrier.
// LDS 27.6 KB -> 19.5 KB (8 blocks/CU). Gate g staged in LDS (stride 72 bf16:
// quad-groups 2-way bank alias only = free per m136).

#define P3_QEA 0          // 64 x 40 bf16  (5120)
#define P3_SL  5120       // 64 x 40 bf16 (S rows vd, 32 d each) (5120)
#define P3_GL  10240      // 64 x 72 bf16 (gate)  (9216)
#define P3_SIZE 19456

__global__ __launch_bounds__(256) void k_phase3rms(const unsigned short* __restrict__ pbuf,
                                                   const unsigned short* __restrict__ obuf,
                                                   const unsigned short* __restrict__ Sp,
                                                   const float* __restrict__ norm_w,
                                                   unsigned short* __restrict__ ybuf) {
  const int bi = blockIdx.x;
  const int c = bi >> 5, bh = bi & 31;
  const int b = bh >> 4, h = bh & 15;
  const int tid = threadIdx.x;
  const int lane = tid & 63, w = tid >> 6;
  const int quad = lane >> 4, l16 = lane & 15;

  __shared__ __align__(16) char sm[P3_SIZE];

  const size_t row0 = (size_t)(b * T_ + c * 64);
  const size_t rq = row0 * NF_ + Q0_ + h * 32;
  const size_t cb = (size_t)c * 32 + bh;

  {
    int i = tid >> 2, seg = tid & 3;
    *(uint4*)(sm + P3_QEA + i * 80 + seg * 16) =
        *(const uint4*)(pbuf + rq + (size_t)i * NF_ + seg * 8);
    *(uint4*)(sm + P3_SL + i * 80 + seg * 16) =
        *(const uint4*)(Sp + cb * 2048 + (size_t)i * 32 + seg * 8);
    const size_t mg = (row0 + i) * NF_ + G0_ + h * 64;
    *(uint4*)(sm + P3_GL + i * 144 + seg * 16)      = *(const uint4*)(pbuf + mg + seg * 8);
    *(uint4*)(sm + P3_GL + i * 144 + 64 + seg * 16) = *(const uint4*)(pbuf + mg + 32 + seg * 8);
  }

  // o_intra fragment load (coalesced, overlaps LDS staging latency)
  float obf[16];
  {
    uint4 o0 = *(const uint4*)(obuf + cb * 4096 + tid * 16);
    uint4 o1 = *(const uint4*)(obuf + cb * 4096 + tid * 16 + 8);
    unpack8(o0, obf);
    unpack8(o1, obf + 8);
  }
  __syncthreads();

  const int tm = w;
  bf16x8 aq = *(const bf16x8*)(sm + P3_QEA + (tm * 16 + l16) * 80 + quad * 16);
  float ov[16];
#pragma unroll
  for (int tn = 0; tn < 4; ++tn) {
    bf16x8 bs = *(const bf16x8*)(sm + P3_SL + (tn * 16 + l16) * 80 + quad * 16);
    f32x4 co = {};
    co = __builtin_amdgcn_mfma_f32_16x16x32_bf16(aq, bs, co, 0, 0, 0);
#pragma unroll
    for (int r = 0; r < 4; ++r)
      ov[tn * 4 + r] = co[r] + obf[tn * 4 + r];
  }

  // in-register row sums: lane holds rows tm*16+quad*4+r, cols tn*16+l16
  float rs[4];
#pragma unroll
  for (int r = 0; r < 4; ++r) {
    float pp = ov[r] * ov[r] + ov[4 + r] * ov[4 + r] +
               ov[8 + r] * ov[8 + r] + ov[12 + r] * ov[12 + r];
    pp += __shfl_xor(pp, 1, 64);
    pp += __shfl_xor(pp, 2, 64);
    pp += __shfl_xor(pp, 4, 64);
    pp += __shfl_xor(pp, 8, 64);
    rs[r] = rsqrtf(pp * (1.0f / 64.0f) + EPS_);
  }

  float nwv[4];
#pragma unroll
  for (int tn = 0; tn < 4; ++tn)
    nwv[tn] = norm_w[tn * 16 + l16];

  // gate + swish + write (per-fragment scalar stores: l16-contiguous 32B runs)
#pragma unroll
  for (int tn = 0; tn < 4; ++tn) {
#pragma unroll
    for (int r = 0; r < 4; ++r) {
      int row = tm * 16 + quad * 4 + r;
      int col = tn * 16 + l16;
      float gv = bf2f(*(const unsigned short*)(sm + P3_GL + row * 144 + col * 2));
      float sw = gv / (1.0f + __expf(-gv));
      ybuf[(row0 + row) * VD_ + h * 64 + col] = f2bf(ov[tn * 4 + r] * rs[r] * nwv[tn] * sw);
    }
  }
}

// ---------------- launch ----------------

extern "C" void kernel_launch(void* const* d_in, const int* in_sizes, int n_in,
                              void* d_out, int out_size, void* d_ws, size_t ws_size,
                              hipStream_t stream) {
  const float* x    = (const float*)d_in[0];
  const float* Wq   = (const float*)d_in[1];
  const float* Wk   = (const float*)d_in[2];
  const float* Wv   = (const float*)d_in[3];
  const float* Wgk1 = (const float*)d_in[4];
  const float* Wgk2 = (const float*)d_in[5];
  const float* bgk  = (const float*)d_in[6];
  const float* Wg   = (const float*)d_in[7];
  const float* nw   = (const float*)d_in[8];
  const float* Wo   = (const float*)d_in[9];
  float* out = (float*)d_out;

  char* p = (char*)d_ws;
  unsigned short* xb   = (unsigned short*)p;  p += (size_t)M_ * D_ * 2;
  unsigned short* Wcat = (unsigned short*)p;  p += (size_t)NF_ * D_ * 2;
  unsigned short* woT  = (unsigned short*)p;  p += (size_t)D_ * VD_ * 2;
  unsigned short* pbuf = (unsigned short*)p;  p += (size_t)M_ * NF_ * 2;
  unsigned short* obuf = (unsigned short*)p;  p += (size_t)M_ * VD_ * 2;
  unsigned short* Ubuf = (unsigned short*)p;  p += (size_t)NC_ * 32 * 2048 * 2;
  unsigned short* Sbuf = (unsigned short*)p;  p += (size_t)NC_ * 32 * 2048 * 2;
  float* dbuf = (float*)p;                    p += (size_t)NC_ * 32 * 32 * 4;
  unsigned short* ybuf = (unsigned short*)p;  p += (size_t)M_ * VD_ * 2;

  // prep: all weight transposes + x f32->bf16 in one launch
  k_prep<<<dim3(32, 32, 14), 256, 0, stream>>>(x, Wq, Wk, Wv, Wg, Wo, Wgk1, xb, Wcat, woT);

  // fused projections: q|k|v|g|glow in one GEMM (bf16 out), XCD-swizzled
  k_gemm_bt<unsigned short><<<(NF_/128) * (M_/128), 256, 0, stream>>>(xb, Wcat, pbuf, M_, NF_, D_);

  // attention (all matmuls MFMA)
  k_phase1<<<NC_ * 32, 256, 0, stream>>>(pbuf, Wgk2, bgk, obuf, Ubuf, dbuf);
  k_phase2<<<256, 128, 0, stream>>>(Ubuf, dbuf, Sbuf);
  k_phase3rms<<<NC_ * 32, 256, 0, stream>>>(pbuf, obuf, Sbuf, nw, ybuf);

  // output projection (f32 out), XCD-swizzled
  k_gemm_bt<float><<<(D_/128) * (M_/128), 256, 0, stream>>>(ybuf, woT, out, M_, D_, VD_);
}